// Round 1
// baseline (231.610 us; speedup 1.0000x reference)
//
#include <hip/hip_runtime.h>

// TaylorActivation: out = Horner(x; c[0..8]), c = w[:,0], order 8.
// x: (512, 65536) fp32 = 33,554,432 elems. Pure streaming elementwise ->
// memory-bound. 268 MB kernel traffic; roofline ~43 us @ 6.3 TB/s.
//
// R1 changes vs baseline (220.6 us session-best):
//  - rocprof showed the timed window is dominated by harness poison-fills
//    (536 MB @ ~80 us each); our kernel is <79 us. Attack the kernel's
//    residual ~62 us -> ~43 us roofline.
//  - CACHED loads (was nontemporal): x (134 MB) fits in 256 MB L3; the
//    6.29 TB/s copy ceiling was measured with cached loads. NT loads force
//    the full HBM path on every read. Stores stay nontemporal (streaming
//    output, no reuse, avoids L2/L3 allocate on the write stream).
//  - VPT 4 -> 8: 8x16B loads in flight per thread (2x MLP), half the
//    blocks, less index math per byte.
//  - Block-uniform full/tail split: hot path has no per-access bounds
//    checks (exact cover: 8,388,608 vec4 = 4096 blocks * 2048).

typedef float f32x4 __attribute__((ext_vector_type(4)));

#define VPT 8  // f32x4 per thread (128 B/thread)

__global__ __launch_bounds__(256) void taylor_poly_kernel(
    const f32x4* __restrict__ x,
    const float* __restrict__ w,   // 9 coefficients, c[i] = w[i]
    f32x4* __restrict__ out,
    int n4)
{
    const float c0 = w[0], c1 = w[1], c2 = w[2], c3 = w[3], c4 = w[4];
    const float c5 = w[5], c6 = w[6], c7 = w[7], c8 = w[8];

    // Base for this block's VPT consecutive coalesced sweeps.
    const int base = blockIdx.x * (blockDim.x * VPT) + threadIdx.x;
    const bool full = (base + (VPT - 1) * blockDim.x) < n4;

    f32x4 v[VPT];

    if (full) {
        // Hot path: branchless, 8 independent cached 16B loads.
#pragma unroll
        for (int k = 0; k < VPT; ++k)
            v[k] = x[base + k * blockDim.x];
    } else {
#pragma unroll
        for (int k = 0; k < VPT; ++k) {
            int i = base + k * blockDim.x;
            if (i < n4) v[k] = x[i];
        }
    }

#pragma unroll
    for (int k = 0; k < VPT; ++k) {
        f32x4 r;
#pragma unroll
        for (int e = 0; e < 4; ++e) {
            float xv = v[k][e];
            float acc = fmaf(c8, xv, c7);
            acc = fmaf(acc, xv, c6);
            acc = fmaf(acc, xv, c5);
            acc = fmaf(acc, xv, c4);
            acc = fmaf(acc, xv, c3);
            acc = fmaf(acc, xv, c2);
            acc = fmaf(acc, xv, c1);
            acc = fmaf(acc, xv, c0);
            r[e] = acc;
        }
        v[k] = r;  // reuse register
    }

    if (full) {
#pragma unroll
        for (int k = 0; k < VPT; ++k)
            __builtin_nontemporal_store(v[k], &out[base + k * blockDim.x]);
    } else {
#pragma unroll
        for (int k = 0; k < VPT; ++k) {
            int i = base + k * blockDim.x;
            if (i < n4) __builtin_nontemporal_store(v[k], &out[i]);
        }
    }
}

extern "C" void kernel_launch(void* const* d_in, const int* in_sizes, int n_in,
                              void* d_out, int out_size, void* d_ws, size_t ws_size,
                              hipStream_t stream) {
    const float* x = (const float*)d_in[0];
    const float* w = (const float*)d_in[1];
    float* out = (float*)d_out;

    int n = in_sizes[0];          // 33,554,432 — divisible by 32
    int n4 = n >> 2;              // 8,388,608 f32x4

    const int block = 256;
    const int elems_per_block = block * VPT;                  // 2048 vec4 / block
    int grid = (n4 + elems_per_block - 1) / elems_per_block;  // 4096

    taylor_poly_kernel<<<grid, block, 0, stream>>>(
        (const f32x4*)x, w, (f32x4*)out, n4);
}